// Round 1
// 974.388 us; speedup vs baseline: 1.0007x; 1.0007x over previous
//
#include <hip/hip_runtime.h>
#include <cstddef>

// Problem shape (fixed by setup_inputs): B=32, S=8192, D=512, fp32.
#define BATCH 32
#define SEQ   8192
#define DIM   512
#define NEG_INF_F (-1e9f)

// Split-S flash decomposition
#define NCHUNK 64
#define SCHUNK (SEQ / NCHUNK)   // 128 rows per (b, chunk) block

// ---------------------------------------------------------------------------
// Fused kernel: one block per (b, s-chunk). 256 threads (4 waves).
//  Phase 1 : scores for 128 rows (wave-per-row dot over D=512)
//  Phase 1b: chunk-local max m_c, weights w=exp(sc-m_c), sum l_c
//  Phase 2 : partial PV with weights -> part[c][b][:], plus m_c/l_c
// K and V are each read exactly once from HBM; no score round-trip.
// ---------------------------------------------------------------------------
__global__ __launch_bounds__(256) void fused_chunk_kernel(
    const float* __restrict__ q, const float* __restrict__ k,
    const float* __restrict__ v, const int* __restrict__ mask,
    float* __restrict__ part,      // [NCHUNK][BATCH][DIM]
    float* __restrict__ mpart,     // [NCHUNK][BATCH]
    float* __restrict__ lpart) {   // [NCHUNK][BATCH]
  __shared__ float sc[SCHUNK];        // raw scores
  __shared__ float wsm[SCHUNK];       // exp-weights
  __shared__ float4 vred[DIM / 4];    // cross-half partial combine (2 KB)

  const int tid  = threadIdx.x;
  const int wave = tid >> 6;          // 0..3
  const int lane = tid & 63;
  const int b  = blockIdx.x >> 6;     // NCHUNK == 64
  const int c  = blockIdx.x & (NCHUNK - 1);
  const int s0 = c * SCHUNK;

  // ---- Phase 1: scores ----------------------------------------------------
  // q row is identical for all 128 rows: load once per wave.
  const float4* __restrict__ q4 = (const float4*)(q + (size_t)b * DIM);
  const float4 q0 = q4[lane];         // floats [4*lane, 4*lane+4)
  const float4 q1 = q4[lane + 64];    // floats [256+4*lane, ...)

  const float4* __restrict__ k4 =
      (const float4*)(k + ((size_t)b * SEQ + s0) * DIM);

  #pragma unroll 2
  for (int r = wave; r < SCHUNK; r += 4) {
    const float4* __restrict__ krow = k4 + (size_t)r * (DIM / 4);
    float4 k0 = krow[lane];           // [0, 1KB): perfectly coalesced
    float4 k1 = krow[lane + 64];      // [1KB, 2KB)
    float d = k0.x * q0.x + k0.y * q0.y + k0.z * q0.z + k0.w * q0.w
            + k1.x * q1.x + k1.y * q1.y + k1.z * q1.z + k1.w * q1.w;
    #pragma unroll
    for (int off = 32; off > 0; off >>= 1) d += __shfl_down(d, off, 64);
    if (lane == 0) {
      int mk = mask[(size_t)b * SEQ + s0 + r];
      sc[r] = mk ? d : NEG_INF_F;
    }
  }
  __syncthreads();

  // ---- Phase 1b: chunk max / exp / sum ------------------------------------
  // Every wave redundantly reduces the full 128 values (covers sc[lane] and
  // sc[lane+64]) via xor-butterfly so all lanes hold the result - no LDS hop.
  const float x0 = sc[lane];
  const float x1 = sc[lane + 64];
  float m = fmaxf(x0, x1);
  #pragma unroll
  for (int off = 32; off > 0; off >>= 1)
    m = fmaxf(m, __shfl_xor(m, off, 64));

  const float w0 = __expf(x0 - m);
  const float w1 = __expf(x1 - m);
  if (wave == 0) { wsm[lane] = w0; wsm[lane + 64] = w1; }

  float ls = w0 + w1;
  #pragma unroll
  for (int off = 32; off > 0; off >>= 1) ls += __shfl_xor(ls, off, 64);

  if (tid == 0) {
    mpart[(size_t)c * BATCH + b] = m;
    lpart[(size_t)c * BATCH + b] = ls;
  }
  __syncthreads();

  // ---- Phase 2: weighted PV partial ---------------------------------------
  // 256 threads = 2 row-groups x 128 float4-columns. Combined, each loop
  // iteration reads rows 2i and 2i+1 fully: 4 KB contiguous per iteration.
  const int cf = tid & 127;           // float4 column 0..127
  const int h  = tid >> 7;            // row-parity group
  const float4* __restrict__ v4 =
      (const float4*)(v + ((size_t)b * SEQ + s0) * DIM);

  float4 acc = {0.f, 0.f, 0.f, 0.f};
  #pragma unroll 4
  for (int i = 0; i < SCHUNK / 2; ++i) {
    const int r = 2 * i + h;
    const float w = wsm[r];           // wave-uniform address -> broadcast
    float4 vv = v4[(size_t)r * (DIM / 4) + cf];
    acc.x += w * vv.x;
    acc.y += w * vv.y;
    acc.z += w * vv.z;
    acc.w += w * vv.w;
  }
  if (h == 1) vred[cf] = acc;
  __syncthreads();
  if (h == 0) {
    float4 o = vred[cf];
    acc.x += o.x; acc.y += o.y; acc.z += o.z; acc.w += o.w;
    ((float4*)part)[((size_t)c * BATCH + b) * (DIM / 4) + cf] = acc;
  }
}

// ---------------------------------------------------------------------------
// Final rescale-reduce across chunks: out[b,:] = sum_c e^{m_c-m} pv_c / L
// One block per batch, 128 threads (one float4 column each).
// ---------------------------------------------------------------------------
__global__ __launch_bounds__(128) void final_reduce_kernel(
    const float* __restrict__ part, const float* __restrict__ mpart,
    const float* __restrict__ lpart, float* __restrict__ out) {
  const int b = blockIdx.x;
  const int t = threadIdx.x;          // float4 column 0..127

  float m = -3.0e38f;
  #pragma unroll
  for (int c = 0; c < NCHUNK; ++c)
    m = fmaxf(m, mpart[(size_t)c * BATCH + b]);

  float L = 0.f;
  float4 acc = {0.f, 0.f, 0.f, 0.f};
  #pragma unroll 4
  for (int c = 0; c < NCHUNK; ++c) {
    const float w = __expf(mpart[(size_t)c * BATCH + b] - m);
    L += w * lpart[(size_t)c * BATCH + b];
    float4 p = ((const float4*)part)[((size_t)c * BATCH + b) * (DIM / 4) + t];
    acc.x += w * p.x;
    acc.y += w * p.y;
    acc.z += w * p.z;
    acc.w += w * p.w;
  }
  const float inv = 1.0f / L;
  float4 o;
  o.x = acc.x * inv; o.y = acc.y * inv; o.z = acc.z * inv; o.w = acc.w * inv;
  ((float4*)out)[(size_t)b * (DIM / 4) + t] = o;
}

// ---------------------------------------------------------------------------
extern "C" void kernel_launch(void* const* d_in, const int* in_sizes, int n_in,
                              void* d_out, int out_size, void* d_ws, size_t ws_size,
                              hipStream_t stream) {
  const float* q    = (const float*)d_in[0];   // [B, D]
  const float* k    = (const float*)d_in[1];   // [B, S, D]
  const float* v    = (const float*)d_in[2];   // [B, S, D]
  const int*   mask = (const int*)d_in[3];     // [B, 1, S]
  float* out = (float*)d_out;                  // [B, D]

  // Workspace: part 4 MB + m/l 8 KB each
  float* part  = (float*)d_ws;                               // NCHUNK*BATCH*DIM
  float* mpart = part + (size_t)NCHUNK * BATCH * DIM;        // NCHUNK*BATCH
  float* lpart = mpart + (size_t)NCHUNK * BATCH;             // NCHUNK*BATCH

  fused_chunk_kernel<<<BATCH * NCHUNK, 256, 0, stream>>>(
      q, k, v, mask, part, mpart, lpart);
  final_reduce_kernel<<<BATCH, 128, 0, stream>>>(part, mpart, lpart, out);
}